// Round 1
// baseline (4298.510 us; speedup 1.0000x reference)
//
#include <hip/hip_runtime.h>
#include <math.h>

#define NNODES 50000
#define DIM 128
#define DEDGE 64

// ---------------------------------------------------------------------------
// edge_index dtype detection: reference says int64, harness doc says int->int32.
// Reading int32 data as int64 fuses two random indices -> huge values; genuine
// int64 indices stay in [0, 50000). Scan a sample, write mode flag to ws.
// ---------------------------------------------------------------------------
__global__ void detect_mode_kernel(const void* __restrict__ ei, int* __restrict__ flag) {
    __shared__ int bad;
    if (threadIdx.x == 0) bad = 0;
    __syncthreads();
    const long long* p = (const long long*)ei;
    int localbad = 0;
    for (int i = threadIdx.x; i < 4096; i += blockDim.x) {
        long long v = p[i];
        if (v < 0 || v >= NNODES) localbad = 1;
    }
    if (localbad) atomicOr(&bad, 1);
    __syncthreads();
    if (threadIdx.x == 0) *flag = bad ? 0 : 1;   // 1 = int64 mode
}

__device__ __forceinline__ int load_idx(const void* ei, long long pos, int mode64) {
    if (mode64) return (int)((const long long*)ei)[pos];
    return ((const int*)ei)[pos];
}

// ---------------------------------------------------------------------------
// Edge message + scatter:  agg[dst] += relu(h[src] + edge_attr @ W + b)
// wave-per-4-edges; W (64x128) staged in LDS; edge_attr row held one element
// per lane, shuffle-broadcast in the K loop; lane owns output cols 2l, 2l+1.
// E assumed divisible by 4 (E = 800000), but guarded anyway.
// ---------------------------------------------------------------------------
__global__ __launch_bounds__(256) void edge_msg_kernel(
    const float* __restrict__ h, const void* __restrict__ ei,
    const int* __restrict__ modep, const float* __restrict__ eattr,
    const float* __restrict__ W, const float* __restrict__ bvec,
    float* __restrict__ agg, int E)
{
    __shared__ float Ws[DEDGE * DIM];
    __shared__ float bs[DIM];
    for (int i = threadIdx.x; i < DEDGE * DIM; i += 256) Ws[i] = W[i];
    if (threadIdx.x < DIM) bs[threadIdx.x] = bvec[threadIdx.x];
    __syncthreads();

    const int mode64 = *modep;
    const int lane = threadIdx.x & 63;
    const int j0 = lane * 2;
    const int wid = blockIdx.x * 4 + (threadIdx.x >> 6);
    const int nw = gridDim.x * 4;

    for (int e0 = wid * 4; e0 < E; e0 += nw * 4) {
        const int ne = min(4, E - e0);
        float a[4];
        int sidx[4], didx[4];
#pragma unroll
        for (int t = 0; t < 4; t++) {
            if (t < ne) {
                long long e = (long long)(e0 + t);
                a[t] = eattr[e * DEDGE + lane];
                sidx[t] = load_idx(ei, e, mode64);
                didx[t] = load_idx(ei, (long long)E + e, mode64);
            } else { a[t] = 0.f; sidx[t] = 0; didx[t] = 0; }
        }
        float2 acc[4];
#pragma unroll
        for (int t = 0; t < 4; t++) acc[t] = make_float2(bs[j0], bs[j0 + 1]);

#pragma unroll
        for (int k = 0; k < DEDGE; k++) {
            float2 w = *(const float2*)&Ws[k * DIM + j0];
#pragma unroll
            for (int t = 0; t < 4; t++) {
                float v = __shfl(a[t], k);
                acc[t].x = fmaf(v, w.x, acc[t].x);
                acc[t].y = fmaf(v, w.y, acc[t].y);
            }
        }
#pragma unroll
        for (int t = 0; t < 4; t++) {
            if (t < ne) {
                float2 hv = *(const float2*)&h[(long long)sidx[t] * DIM + j0];
                float m0 = fmaxf(acc[t].x + hv.x, 0.f);
                float m1 = fmaxf(acc[t].y + hv.y, 0.f);
                float* dst = &agg[(long long)didx[t] * DIM + j0];
                unsafeAtomicAdd(dst, m0);
                unsafeAtomicAdd(dst + 1, m1);
            }
        }
    }
}

// ---------------------------------------------------------------------------
// GIN update:  hout = act( [agg | (1+eps)*h] @ W(256x128) + b )
// wave-per-4-nodes; cat vector held 4 regs/lane (one per 64-chunk), W streamed
// from global (L2-resident, 128 KB). relu_flag: 0 -> leaky(0.2), 1 -> relu
// (relu(leaky(z)) == relu(z), so layer 1 emits relu'd features directly).
// ---------------------------------------------------------------------------
__global__ __launch_bounds__(256) void node_update_kernel(
    const float* __restrict__ agg, const float* __restrict__ h,
    const float* __restrict__ W, const float* __restrict__ bvec,
    const float* __restrict__ epsp, float* __restrict__ hout,
    int relu_flag)
{
    const int lane = threadIdx.x & 63;
    const int j0 = lane * 2;
    const float s = 1.0f + epsp[0];
    const int wid = blockIdx.x * 4 + (threadIdx.x >> 6);
    const int nw = gridDim.x * 4;
    const float2* Wv = (const float2*)W;   // [256][64] float2
    const float b0 = bvec[j0], b1 = bvec[j0 + 1];

    for (int n0 = wid * 4; n0 < NNODES; n0 += nw * 4) {
        float cr0[4], cr1[4], cr2[4], cr3[4];
#pragma unroll
        for (int t = 0; t < 4; t++) {
            int n = n0 + t;
            cr0[t] = agg[n * DIM + lane];
            cr1[t] = agg[n * DIM + lane + 64];
            cr2[t] = s * h[n * DIM + lane];
            cr3[t] = s * h[n * DIM + lane + 64];
        }
        float2 acc[4];
#pragma unroll
        for (int t = 0; t < 4; t++) acc[t] = make_float2(b0, b1);

#pragma unroll
        for (int r = 0; r < 4; r++) {
#pragma unroll 16
            for (int sl = 0; sl < 64; sl++) {
                int k = r * 64 + sl;
                float2 w = Wv[k * 64 + lane];
#pragma unroll
                for (int t = 0; t < 4; t++) {
                    float v;
                    if (r == 0) v = __shfl(cr0[t], sl);
                    else if (r == 1) v = __shfl(cr1[t], sl);
                    else if (r == 2) v = __shfl(cr2[t], sl);
                    else v = __shfl(cr3[t], sl);
                    acc[t].x = fmaf(v, w.x, acc[t].x);
                    acc[t].y = fmaf(v, w.y, acc[t].y);
                }
            }
        }
#pragma unroll
        for (int t = 0; t < 4; t++) {
            float z0 = acc[t].x, z1 = acc[t].y;
            if (relu_flag) { z0 = fmaxf(z0, 0.f); z1 = fmaxf(z1, 0.f); }
            else { z0 = z0 > 0.f ? z0 : 0.2f * z0; z1 = z1 > 0.f ? z1 : 0.2f * z1; }
            *(float2*)&hout[(n0 + t) * DIM + j0] = make_float2(z0, z1);
        }
    }
}

// ---------------------------------------------------------------------------
// Edge head: he = h[src]*h[dst] (h already relu'd); write he;
// z = leaky(he @ W1 + b1); logits = z @ W2 + b2; yhat = softmax2(logits).
// wave-per-8-edges; W1 (128x128, 64 KB) in LDS; W2/b1/b2 slices in regs.
// ---------------------------------------------------------------------------
__global__ __launch_bounds__(256) void edge_head_kernel(
    const float* __restrict__ h, const void* __restrict__ ei,
    const int* __restrict__ modep,
    const float* __restrict__ W1, const float* __restrict__ b1,
    const float* __restrict__ W2, const float* __restrict__ b2,
    float* __restrict__ out_he, float* __restrict__ out_y, int E)
{
    __shared__ float W1s[DIM * DIM];   // 64 KB
    for (int i = threadIdx.x; i < DIM * DIM; i += 256) W1s[i] = W1[i];
    __syncthreads();

    const int mode64 = *modep;
    const int lane = threadIdx.x & 63;
    const int j0 = lane * 2;
    const float bb0 = b1[j0], bb1 = b1[j0 + 1];
    const float w200 = W2[j0 * 2 + 0], w201 = W2[j0 * 2 + 1];
    const float w210 = W2[(j0 + 1) * 2 + 0], w211 = W2[(j0 + 1) * 2 + 1];
    const float c0 = b2[0], c1 = b2[1];
    const int wid = blockIdx.x * 4 + (threadIdx.x >> 6);
    const int nw = gridDim.x * 4;
    const int EPW = 8;

    for (int e0 = wid * EPW; e0 < E; e0 += nw * EPW) {
        const int ne = min(EPW, E - e0);
        float he0[EPW], he1[EPW];
#pragma unroll
        for (int t = 0; t < EPW; t++) {
            if (t < ne) {
                long long e = (long long)(e0 + t);
                int si = load_idx(ei, e, mode64);
                int di = load_idx(ei, (long long)E + e, mode64);
                float2 hs = *(const float2*)&h[(long long)si * DIM + j0];
                float2 hd = *(const float2*)&h[(long long)di * DIM + j0];
                he0[t] = hs.x * hd.x;
                he1[t] = hs.y * hd.y;
                *(float2*)&out_he[e * DIM + j0] = make_float2(he0[t], he1[t]);
            } else { he0[t] = 0.f; he1[t] = 0.f; }
        }
        float z0[EPW], z1[EPW];
#pragma unroll
        for (int t = 0; t < EPW; t++) { z0[t] = bb0; z1[t] = bb1; }

#pragma unroll 8
        for (int sl = 0; sl < 64; sl++) {
            float2 wA = *(const float2*)&W1s[(2 * sl) * DIM + j0];
            float2 wB = *(const float2*)&W1s[(2 * sl + 1) * DIM + j0];
#pragma unroll
            for (int t = 0; t < EPW; t++) {
                float p = __shfl(he0[t], sl);
                float q = __shfl(he1[t], sl);
                z0[t] = fmaf(p, wA.x, z0[t]); z1[t] = fmaf(p, wA.y, z1[t]);
                z0[t] = fmaf(q, wB.x, z0[t]); z1[t] = fmaf(q, wB.y, z1[t]);
            }
        }
#pragma unroll
        for (int t = 0; t < EPW; t++) {
            if (t >= ne) break;
            float za = z0[t] > 0.f ? z0[t] : 0.2f * z0[t];
            float zb = z1[t] > 0.f ? z1[t] : 0.2f * z1[t];
            float p0 = za * w200 + zb * w210;
            float p1 = za * w201 + zb * w211;
#pragma unroll
            for (int m = 32; m; m >>= 1) { p0 += __shfl_xor(p0, m); p1 += __shfl_xor(p1, m); }
            float l0 = p0 + c0, l1 = p1 + c1;
            float mx = fmaxf(l0, l1);
            float ex0 = __expf(l0 - mx), ex1 = __expf(l1 - mx);
            float inv = 1.f / (ex0 + ex1);
            if (lane == 0) {
                out_y[(long long)(e0 + t) * 2 + 0] = ex0 * inv;
                out_y[(long long)(e0 + t) * 2 + 1] = ex1 * inv;
            }
        }
    }
}

extern "C" void kernel_launch(void* const* d_in, const int* in_sizes, int n_in,
                              void* d_out, int out_size, void* d_ws, size_t ws_size,
                              hipStream_t stream)
{
    const float* x     = (const float*)d_in[0];
    const void*  ei    = d_in[1];
    const float* eattr = (const float*)d_in[2];
    const float* aW0   = (const float*)d_in[3];
    const float* ab0   = (const float*)d_in[4];
    const float* mW0   = (const float*)d_in[5];
    const float* mb0   = (const float*)d_in[6];
    const float* eps0  = (const float*)d_in[7];
    const float* aW1   = (const float*)d_in[8];
    const float* ab1   = (const float*)d_in[9];
    const float* mW1   = (const float*)d_in[10];
    const float* mb1   = (const float*)d_in[11];
    const float* eps1  = (const float*)d_in[12];
    const float* lpW1  = (const float*)d_in[13];
    const float* lpb1  = (const float*)d_in[14];
    const float* lpW2  = (const float*)d_in[15];
    const float* lpb2  = (const float*)d_in[16];

    const int E = in_sizes[1] / 2;

    float* wsf  = (float*)d_ws;
    int*   flag = (int*)d_ws;
    float* agg  = wsf + 64;
    float* h1   = agg + (size_t)NNODES * DIM;
    float* h2   = h1 + (size_t)NNODES * DIM;
    float* out_he = (float*)d_out;
    float* out_y  = out_he + (long long)E * DIM;

    detect_mode_kernel<<<1, 256, 0, stream>>>(ei, flag);

    // ---- layer 0 ----
    hipMemsetAsync(agg, 0, (size_t)NNODES * DIM * sizeof(float), stream);
    edge_msg_kernel<<<2048, 256, 0, stream>>>(x, ei, flag, eattr, aW0, ab0, agg, E);
    node_update_kernel<<<1024, 256, 0, stream>>>(agg, x, mW0, mb0, eps0, h1, 0);

    // ---- layer 1 ----
    hipMemsetAsync(agg, 0, (size_t)NNODES * DIM * sizeof(float), stream);
    edge_msg_kernel<<<2048, 256, 0, stream>>>(h1, ei, flag, eattr, aW1, ab1, agg, E);
    node_update_kernel<<<1024, 256, 0, stream>>>(agg, h1, mW1, mb1, eps1, h2, 1);

    // ---- link predictor head ----
    edge_head_kernel<<<2048, 256, 0, stream>>>(h2, ei, flag, lpW1, lpb1, lpW2, lpb2,
                                               out_he, out_y, E);
}

// Round 2
// 1446.779 us; speedup vs baseline: 2.9711x; 2.9711x over previous
//
#include <hip/hip_runtime.h>
#include <math.h>

#define NNODES 50000
#define DIM 128
#define DEDGE 64

typedef __attribute__((ext_vector_type(8))) short bf16x8;
typedef __attribute__((ext_vector_type(4))) float f32x4;

// ---------------------------------------------------------------------------
// edge_index dtype detection (int64 per reference vs int32 per harness doc)
// ---------------------------------------------------------------------------
__global__ void detect_mode_kernel(const void* __restrict__ ei, int* __restrict__ flag) {
    __shared__ int bad;
    if (threadIdx.x == 0) bad = 0;
    __syncthreads();
    const long long* p = (const long long*)ei;
    int localbad = 0;
    for (int i = threadIdx.x; i < 4096; i += blockDim.x) {
        long long v = p[i];
        if (v < 0 || v >= NNODES) localbad = 1;
    }
    if (localbad) atomicOr(&bad, 1);
    __syncthreads();
    if (threadIdx.x == 0) *flag = bad ? 0 : 1;   // 1 = int64 mode
}

__device__ __forceinline__ int load_idx(const void* ei, long long pos, int mode64) {
    if (mode64) return (int)((const long long*)ei)[pos];
    return ((const int*)ei)[pos];
}

// ---------------------------------------------------------------------------
// split f32 -> bf16 hi (RTZ) + bf16 lo (RTN of remainder); hi+lo ~ 2^-17 rel
// ---------------------------------------------------------------------------
__device__ __forceinline__ void split_bf16(float f, short& hi, short& lo) {
    union { float f; unsigned u; } v; v.f = f;
    unsigned uh = v.u & 0xFFFF0000u;
    hi = (short)(uh >> 16);
    union { unsigned u; float f; } hh; hh.u = uh;
    float r = f - hh.f;
    union { float f; unsigned u; } w; w.f = r;
    unsigned t = w.u + 0x7FFFu + ((w.u >> 16) & 1u);
    lo = (short)(t >> 16);
}

__device__ __forceinline__ void build_frag(const float* p, bf16x8& hi, bf16x8& lo) {
    f32x4 v0 = *(const f32x4*)p;
    f32x4 v1 = *(const f32x4*)(p + 4);
#pragma unroll
    for (int i = 0; i < 4; i++) { short h, l; split_bf16(v0[i], h, l); hi[i] = h; lo[i] = l; }
#pragma unroll
    for (int i = 0; i < 4; i++) { short h, l; split_bf16(v1[i], h, l); hi[4 + i] = h; lo[4 + i] = l; }
}

// ---------------------------------------------------------------------------
// prep: transpose weights to WT[col][k], split to hi/lo bf16, into ws.
// regions (shorts): aW0hi@0 aW0lo@8192 aW1hi@16384 aW1lo@24576
//                   mW0hi@32768 mW0lo@65536 mW1hi@98304 mW1lo@131072
//                   lpW1hi@163840 lpW1lo@180224   (total 196608 shorts)
// ---------------------------------------------------------------------------
__global__ void prep_weights(const float* __restrict__ aW0, const float* __restrict__ aW1,
                             const float* __restrict__ mW0, const float* __restrict__ mW1,
                             const float* __restrict__ lpW1, short* __restrict__ wt)
{
    int i = blockIdx.x * 256 + threadIdx.x;   // 0..98303 (384 blocks)
    const float* src; int K, hioff, looff, j;
    if (i < 8192)        { src = aW0;  K = 64;  hioff = 0;      looff = 8192;   j = i; }
    else if (i < 16384)  { src = aW1;  K = 64;  hioff = 16384;  looff = 24576;  j = i - 8192; }
    else if (i < 49152)  { src = mW0;  K = 256; hioff = 32768;  looff = 65536;  j = i - 16384; }
    else if (i < 81920)  { src = mW1;  K = 256; hioff = 98304;  looff = 131072; j = i - 49152; }
    else                 { src = lpW1; K = 128; hioff = 163840; looff = 180224; j = i - 81920; }
    int col = j / K, k = j % K;
    float f = src[k * DIM + col];
    short hi, lo; split_bf16(f, hi, lo);
    wt[hioff + col * K + k] = hi;
    wt[looff + col * K + k] = lo;
}

// ---------------------------------------------------------------------------
// edge message + scatter: agg[dst] += relu(h[src] + eattr @ W + b)
// wave-per-16-edges MFMA; result staged per-wave in LDS; epilogue does
// row-contiguous 256B atomic bursts.
// ---------------------------------------------------------------------------
__global__ __launch_bounds__(256, 4) void edge_msg_mfma(
    const float* __restrict__ h, const void* __restrict__ ei,
    const int* __restrict__ modep, const float* __restrict__ eattr,
    const short* __restrict__ Whi, const short* __restrict__ Wlo,
    const float* __restrict__ bvec, float* __restrict__ agg, int E)
{
    __shared__ float e_lds[4][16][132];
    const int mode64 = *modep;
    const int lane = threadIdx.x & 63;
    const int w = threadIdx.x >> 6;
    const int lg = lane >> 4, lr = lane & 15;
    const long long e0 = ((long long)blockIdx.x * 4 + w) * 16;
    if (e0 >= E) return;

    const long long erow = (e0 + lr < E) ? (e0 + lr) : (E - 1);
    int sidx = load_idx(ei, erow, mode64);
    int didx = load_idx(ei, (long long)E + erow, mode64);

    f32x4 acc[8];
#pragma unroll
    for (int n = 0; n < 8; n++) {
        float b = bvec[n * 16 + lr];
        acc[n] = (f32x4){b, b, b, b};
    }
    bf16x8 ahi[2], alo[2];
#pragma unroll
    for (int kc = 0; kc < 2; kc++)
        build_frag(eattr + erow * DEDGE + kc * 32 + lg * 8, ahi[kc], alo[kc]);

#pragma unroll
    for (int n = 0; n < 8; n++) {
#pragma unroll
        for (int kc = 0; kc < 2; kc++) {
            const int off = (n * 16 + lr) * DEDGE + kc * 32 + lg * 8;
            bf16x8 bh = *(const bf16x8*)(Whi + off);
            bf16x8 bl = *(const bf16x8*)(Wlo + off);
            acc[n] = __builtin_amdgcn_mfma_f32_16x16x32_bf16(ahi[kc], bh, acc[n], 0, 0, 0);
            acc[n] = __builtin_amdgcn_mfma_f32_16x16x32_bf16(alo[kc], bh, acc[n], 0, 0, 0);
            acc[n] = __builtin_amdgcn_mfma_f32_16x16x32_bf16(ahi[kc], bl, acc[n], 0, 0, 0);
        }
    }
    // D layout: col = n*16+lr, row = lg*4+r
#pragma unroll
    for (int n = 0; n < 8; n++)
#pragma unroll
        for (int r = 0; r < 4; r++)
            e_lds[w][lg * 4 + r][n * 16 + lr] = acc[n][r];

    for (int r = 0; r < 16; r++) {
        long long e = e0 + r;
        if (e >= E) break;
        int si = __shfl(sidx, r);
        int di = __shfl(didx, r);
        float ev0 = e_lds[w][r][lane];
        float ev1 = e_lds[w][r][64 + lane];
        float m0 = fmaxf(ev0 + h[(long long)si * DIM + lane], 0.f);
        float m1 = fmaxf(ev1 + h[(long long)si * DIM + 64 + lane], 0.f);
        unsafeAtomicAdd(&agg[(long long)di * DIM + lane], m0);
        unsafeAtomicAdd(&agg[(long long)di * DIM + 64 + lane], m1);
    }
}

// ---------------------------------------------------------------------------
// GIN update: hout = act([agg | (1+eps)*h] @ W(256x128) + b), wave-per-16-nodes
// ---------------------------------------------------------------------------
__global__ __launch_bounds__(256, 4) void node_update_mfma(
    const float* __restrict__ agg, const float* __restrict__ h,
    const short* __restrict__ Whi, const short* __restrict__ Wlo,
    const float* __restrict__ bvec, const float* __restrict__ epsp,
    float* __restrict__ hout, int relu_flag)
{
    const int lane = threadIdx.x & 63;
    const int w = threadIdx.x >> 6;
    const int lg = lane >> 4, lr = lane & 15;
    const int n0 = (blockIdx.x * 4 + w) * 16;
    if (n0 >= NNODES) return;
    const float s = 1.0f + epsp[0];
    const int arow = (n0 + lr < NNODES) ? (n0 + lr) : (NNODES - 1);

    f32x4 acc[8];
#pragma unroll
    for (int n = 0; n < 8; n++) {
        float b = bvec[n * 16 + lr];
        acc[n] = (f32x4){b, b, b, b};
    }
#pragma unroll
    for (int kc = 0; kc < 8; kc++) {
        const int k = kc * 32 + lg * 8;
        float buf[8];
        if (k < 128) {
            f32x4 v0 = *(const f32x4*)(agg + (long long)arow * DIM + k);
            f32x4 v1 = *(const f32x4*)(agg + (long long)arow * DIM + k + 4);
#pragma unroll
            for (int i = 0; i < 4; i++) { buf[i] = v0[i]; buf[4 + i] = v1[i]; }
        } else {
            f32x4 v0 = *(const f32x4*)(h + (long long)arow * DIM + (k - 128));
            f32x4 v1 = *(const f32x4*)(h + (long long)arow * DIM + (k - 128) + 4);
#pragma unroll
            for (int i = 0; i < 4; i++) { buf[i] = s * v0[i]; buf[4 + i] = s * v1[i]; }
        }
        bf16x8 ahi, alo;
#pragma unroll
        for (int i = 0; i < 8; i++) { short hh, ll; split_bf16(buf[i], hh, ll); ahi[i] = hh; alo[i] = ll; }
#pragma unroll
        for (int n = 0; n < 8; n++) {
            const int off = (n * 16 + lr) * 256 + k;
            bf16x8 bh = *(const bf16x8*)(Whi + off);
            bf16x8 bl = *(const bf16x8*)(Wlo + off);
            acc[n] = __builtin_amdgcn_mfma_f32_16x16x32_bf16(ahi, bh, acc[n], 0, 0, 0);
            acc[n] = __builtin_amdgcn_mfma_f32_16x16x32_bf16(alo, bh, acc[n], 0, 0, 0);
            acc[n] = __builtin_amdgcn_mfma_f32_16x16x32_bf16(ahi, bl, acc[n], 0, 0, 0);
        }
    }
#pragma unroll
    for (int n = 0; n < 8; n++) {
#pragma unroll
        for (int r = 0; r < 4; r++) {
            int row = n0 + lg * 4 + r;
            if (row < NNODES) {
                float z = acc[n][r];
                z = relu_flag ? fmaxf(z, 0.f) : (z > 0.f ? z : 0.2f * z);
                hout[(long long)row * DIM + n * 16 + lr] = z;
            }
        }
    }
}

// ---------------------------------------------------------------------------
// edge head: he = h[src]*h[dst] (write f32), z = leaky(he@W1+b1),
// logits = z@W2+b2, yhat = softmax2. wave-per-16-edges MFMA, no LDS.
// ---------------------------------------------------------------------------
__global__ __launch_bounds__(256, 4) void edge_head_mfma(
    const float* __restrict__ h, const void* __restrict__ ei,
    const int* __restrict__ modep,
    const short* __restrict__ W1hi, const short* __restrict__ W1lo,
    const float* __restrict__ b1, const float* __restrict__ W2,
    const float* __restrict__ b2,
    float* __restrict__ out_he, float* __restrict__ out_y, int E)
{
    const int mode64 = *modep;
    const int lane = threadIdx.x & 63;
    const int w = threadIdx.x >> 6;
    const int lg = lane >> 4, lr = lane & 15;
    const long long e0 = ((long long)blockIdx.x * 4 + w) * 16;
    if (e0 >= E) return;
    const long long erow = (e0 + lr < E) ? (e0 + lr) : (E - 1);
    int si = load_idx(ei, erow, mode64);
    int di = load_idx(ei, (long long)E + erow, mode64);

    f32x4 acc[8];
#pragma unroll
    for (int n = 0; n < 8; n++) {
        float b = b1[n * 16 + lr];
        acc[n] = (f32x4){b, b, b, b};
    }
    bf16x8 ahi[4], alo[4];
#pragma unroll
    for (int kc = 0; kc < 4; kc++) {
        const int k = kc * 32 + lg * 8;
        f32x4 a0 = *(const f32x4*)(h + (long long)si * DIM + k);
        f32x4 a1 = *(const f32x4*)(h + (long long)si * DIM + k + 4);
        f32x4 c0 = *(const f32x4*)(h + (long long)di * DIM + k);
        f32x4 c1 = *(const f32x4*)(h + (long long)di * DIM + k + 4);
        f32x4 p0, p1;
#pragma unroll
        for (int i = 0; i < 4; i++) { p0[i] = a0[i] * c0[i]; p1[i] = a1[i] * c1[i]; }
        if (e0 + lr < E) {
            *(f32x4*)(out_he + erow * DIM + k) = p0;
            *(f32x4*)(out_he + erow * DIM + k + 4) = p1;
        }
#pragma unroll
        for (int i = 0; i < 4; i++) {
            short hh, ll;
            split_bf16(p0[i], hh, ll); ahi[kc][i] = hh; alo[kc][i] = ll;
            split_bf16(p1[i], hh, ll); ahi[kc][4 + i] = hh; alo[kc][4 + i] = ll;
        }
    }
#pragma unroll
    for (int n = 0; n < 8; n++) {
#pragma unroll
        for (int kc = 0; kc < 4; kc++) {
            const int off = (n * 16 + lr) * 128 + kc * 32 + lg * 8;
            bf16x8 bh = *(const bf16x8*)(W1hi + off);
            bf16x8 bl = *(const bf16x8*)(W1lo + off);
            acc[n] = __builtin_amdgcn_mfma_f32_16x16x32_bf16(ahi[kc], bh, acc[n], 0, 0, 0);
            acc[n] = __builtin_amdgcn_mfma_f32_16x16x32_bf16(alo[kc], bh, acc[n], 0, 0, 0);
            acc[n] = __builtin_amdgcn_mfma_f32_16x16x32_bf16(ahi[kc], bl, acc[n], 0, 0, 0);
        }
    }
    // logits: leaky(z) dotted with W2 cols, reduce over the 16 cols (lr)
    float q0[4] = {0.f, 0.f, 0.f, 0.f}, q1[4] = {0.f, 0.f, 0.f, 0.f};
#pragma unroll
    for (int n = 0; n < 8; n++) {
        float w2a = W2[(n * 16 + lr) * 2 + 0];
        float w2b = W2[(n * 16 + lr) * 2 + 1];
#pragma unroll
        for (int r = 0; r < 4; r++) {
            float z = acc[n][r];
            z = z > 0.f ? z : 0.2f * z;
            q0[r] = fmaf(z, w2a, q0[r]);
            q1[r] = fmaf(z, w2b, q1[r]);
        }
    }
#pragma unroll
    for (int m = 1; m < 16; m <<= 1) {
#pragma unroll
        for (int r = 0; r < 4; r++) {
            q0[r] += __shfl_xor(q0[r], m);
            q1[r] += __shfl_xor(q1[r], m);
        }
    }
    if (lr == 0) {
        float c0 = b2[0], c1 = b2[1];
#pragma unroll
        for (int r = 0; r < 4; r++) {
            long long e = e0 + lg * 4 + r;
            if (e < E) {
                float l0 = q0[r] + c0, l1 = q1[r] + c1;
                float mx = fmaxf(l0, l1);
                float x0 = expf(l0 - mx), x1 = expf(l1 - mx);
                float inv = 1.f / (x0 + x1);
                out_y[e * 2 + 0] = x0 * inv;
                out_y[e * 2 + 1] = x1 * inv;
            }
        }
    }
}

extern "C" void kernel_launch(void* const* d_in, const int* in_sizes, int n_in,
                              void* d_out, int out_size, void* d_ws, size_t ws_size,
                              hipStream_t stream)
{
    const float* x     = (const float*)d_in[0];
    const void*  ei    = d_in[1];
    const float* eattr = (const float*)d_in[2];
    const float* aW0   = (const float*)d_in[3];
    const float* ab0   = (const float*)d_in[4];
    const float* mW0   = (const float*)d_in[5];
    const float* mb0   = (const float*)d_in[6];
    const float* eps0  = (const float*)d_in[7];
    const float* aW1   = (const float*)d_in[8];
    const float* ab1   = (const float*)d_in[9];
    const float* mW1   = (const float*)d_in[10];
    const float* mb1   = (const float*)d_in[11];
    const float* eps1  = (const float*)d_in[12];
    const float* lpW1  = (const float*)d_in[13];
    const float* lpb1  = (const float*)d_in[14];
    const float* lpW2  = (const float*)d_in[15];
    const float* lpb2  = (const float*)d_in[16];

    const int E = in_sizes[1] / 2;

    float* wsf  = (float*)d_ws;
    int*   flag = (int*)d_ws;
    float* agg  = wsf + 64;
    float* h1   = agg + (size_t)NNODES * DIM;
    float* h2   = h1 + (size_t)NNODES * DIM;
    short* wt   = (short*)(h2 + (size_t)NNODES * DIM);
    float* out_he = (float*)d_out;
    float* out_y  = out_he + (long long)E * DIM;

    const short* aW0hi = wt,          *aW0lo = wt + 8192;
    const short* aW1hi = wt + 16384,  *aW1lo = wt + 24576;
    const short* mW0hi = wt + 32768,  *mW0lo = wt + 65536;
    const short* mW1hi = wt + 98304,  *mW1lo = wt + 131072;
    const short* lpW1hi = wt + 163840, *lpW1lo = wt + 180224;

    detect_mode_kernel<<<1, 256, 0, stream>>>(ei, flag);
    prep_weights<<<384, 256, 0, stream>>>(aW0, aW1, mW0, mW1, lpW1, wt);

    const int eblocks = (E + 63) / 64;
    const int nblocks = (NNODES + 63) / 64;

    // ---- layer 0 ----
    hipMemsetAsync(agg, 0, (size_t)NNODES * DIM * sizeof(float), stream);
    edge_msg_mfma<<<eblocks, 256, 0, stream>>>(x, ei, flag, eattr, aW0hi, aW0lo, ab0, agg, E);
    node_update_mfma<<<nblocks, 256, 0, stream>>>(agg, x, mW0hi, mW0lo, mb0, eps0, h1, 0);

    // ---- layer 1 ----
    hipMemsetAsync(agg, 0, (size_t)NNODES * DIM * sizeof(float), stream);
    edge_msg_mfma<<<eblocks, 256, 0, stream>>>(h1, ei, flag, eattr, aW1hi, aW1lo, ab1, agg, E);
    node_update_mfma<<<nblocks, 256, 0, stream>>>(agg, h1, mW1hi, mW1lo, mb1, eps1, h2, 1);

    // ---- link predictor head ----
    edge_head_mfma<<<eblocks, 256, 0, stream>>>(h2, ei, flag, lpW1hi, lpW1lo, lpb1, lpW2, lpb2,
                                                out_he, out_y, E);
}